// Round 14
// baseline (362.168 us; speedup 1.0000x reference)
//
#include <hip/hip_runtime.h>
#include <hip/hip_bf16.h>

#define LEAKY 0.2f
#define BINB 8          // 256 nodes per bin (requires N <= 65536 for u16 packing)
#define TILE 2048       // edges per block in binning kernels
#define CAP 8192        // LDS bucket-segment capacity per bin (avg ~4081)

static inline int ceil_div(int a, int b) { return (a + b - 1) / b; }

typedef __bf16 bf16x8 __attribute__((ext_vector_type(8)));
typedef float f32x4 __attribute__((ext_vector_type(4)));

// f32 -> bf16 bits, round-to-nearest-even
__device__ __forceinline__ ushort f2bf(float f) {
    unsigned int x = __float_as_uint(f);
    unsigned int r = (x + 0x7fffu + ((x >> 16) & 1u)) >> 16;
    return (ushort)r;
}
__device__ __forceinline__ float bflo(unsigned int u) { return __uint_as_float(u << 16); }
__device__ __forceinline__ float bfhi(unsigned int u) { return __uint_as_float(u & 0xffff0000u); }

// ---------------- CSR build (two-level, coalesced writes) ----------------
// Round-4 lesson: one-pass random 4B scatter = 17x HBM write amplification.

__global__ __launch_bounds__(256) void bin_count(const int* __restrict__ dst,
                                                 int* __restrict__ bin_cnt, int E, int NB) {
    __shared__ int h[256];
    int t = threadIdx.x;
    h[t] = 0;
    __syncthreads();
    int base = blockIdx.x * TILE;
#pragma unroll
    for (int j = 0; j < TILE / 256; ++j) {
        int i = base + j * 256 + t;
        if (i < E) atomicAdd(&h[dst[i] >> BINB], 1);
    }
    __syncthreads();
    if (t < NB && h[t]) atomicAdd(&bin_cnt[t], h[t]);
}

__global__ __launch_bounds__(256) void bin_scan(const int* __restrict__ bin_cnt,
                                                int* __restrict__ binStart,
                                                int* __restrict__ bin_cursor,
                                                int* __restrict__ rowstart,
                                                int NB, int N, int E) {
    __shared__ int s[256];
    int t = threadIdx.x;
    int v = (t < NB) ? bin_cnt[t] : 0;
    s[t] = v;
    __syncthreads();
    for (int off = 1; off < 256; off <<= 1) {
        int x = (t >= off) ? s[t - off] : 0;
        __syncthreads();
        s[t] += x;
        __syncthreads();
    }
    int excl = s[t] - v;
    if (t < NB) {
        binStart[t] = excl;
        bin_cursor[t] = excl;
        if (t == NB - 1) binStart[NB] = excl + v;
    }
    if (t == 0) rowstart[N] = E;
}

__global__ __launch_bounds__(256) void bin_scatter(const int* __restrict__ src,
                                                   const int* __restrict__ dst,
                                                   int* __restrict__ bin_cursor,
                                                   unsigned int* __restrict__ coarse, int E) {
    __shared__ int hist[256], scn[256], gbase[256], lcur[256];
    __shared__ unsigned int outp[TILE];
    __shared__ int gidx[TILE];
    int t = threadIdx.x;
    hist[t] = 0;
    __syncthreads();
    int base = blockIdx.x * TILE;
    int dloc[TILE / 256];
#pragma unroll
    for (int j = 0; j < TILE / 256; ++j) {
        int i = base + j * 256 + t;
        int d = (i < E) ? dst[i] : -1;
        dloc[j] = d;
        if (d >= 0) atomicAdd(&hist[d >> BINB], 1);
    }
    __syncthreads();
    int hv = hist[t];
    scn[t] = hv;
    __syncthreads();
    for (int off = 1; off < 256; off <<= 1) {
        int x = (t >= off) ? scn[t - off] : 0;
        __syncthreads();
        scn[t] += x;
        __syncthreads();
    }
    int excl = scn[t] - hv;
    if (hv > 0) gbase[t] = atomicAdd(&bin_cursor[t], hv);
    lcur[t] = excl;
    scn[t] = excl;
    __syncthreads();
#pragma unroll
    for (int j = 0; j < TILE / 256; ++j) {
        int i = base + j * 256 + t;
        int d = dloc[j];
        if (d >= 0) {
            int b = d >> BINB;
            int pos = atomicAdd(&lcur[b], 1);
            outp[pos] = (unsigned int)src[i] | ((unsigned int)(d & ((1 << BINB) - 1)) << 16);
            gidx[pos] = gbase[b] + (pos - scn[b]);
        }
    }
    __syncthreads();
    int cnt = min(TILE, E - base);
    for (int j = t; j < cnt; j += 256) coarse[gidx[j]] = outp[j];
}

// Also emits dst16[j] = global dst node of CSR slot j (needed by edge_weights).
__global__ __launch_bounds__(256) void fine_csr(const unsigned int* __restrict__ coarse,
                                                const int* __restrict__ binStart,
                                                int* __restrict__ rowstart,
                                                ushort* __restrict__ bucket,
                                                ushort* __restrict__ dst16, int N) {
    __shared__ int hist[256], scn[256], cur[256];
    __shared__ ushort sb[CAP];
    __shared__ ushort db[CAP];
    int b = blockIdx.x, t = threadIdx.x;
    int e0 = binStart[b], e1 = binStart[b + 1];
    int cnt = e1 - e0;
    hist[t] = 0;
    __syncthreads();
    for (int j = e0 + t; j < e1; j += 256) atomicAdd(&hist[coarse[j] >> 16], 1);
    __syncthreads();
    int hv = hist[t];
    scn[t] = hv;
    __syncthreads();
    for (int off = 1; off < 256; off <<= 1) {
        int x = (t >= off) ? scn[t - off] : 0;
        __syncthreads();
        scn[t] += x;
        __syncthreads();
    }
    int excl = scn[t] - hv;
    int n = (b << BINB) + t;
    if (n < N) rowstart[n] = e0 + excl;
    cur[t] = excl;
    __syncthreads();
    bool fit = (cnt <= CAP);
    for (int j = e0 + t; j < e1; j += 256) {
        unsigned int p = coarse[j];
        int dl = p >> 16;
        int pos = atomicAdd(&cur[dl], 1);
        ushort sv = (ushort)(p & 0xffffu);
        ushort dv = (ushort)((b << BINB) | dl);
        if (fit) {
            sb[pos] = sv;
            db[pos] = dv;
        } else {
            bucket[e0 + pos] = sv;
            dst16[e0 + pos] = dv;
        }
    }
    __syncthreads();
    if (fit) {
        for (int j = t; j < cnt; j += 256) {
            bucket[e0 + j] = sb[j];
            dst16[e0 + j] = db[j];
        }
    }
}

// ---------------- W convert: Wt[n][k] = bf16(W[k][n]) ----------------
__global__ __launch_bounds__(256) void convert_w(const float* __restrict__ W1,
                                                 const float* __restrict__ W2,
                                                 ushort* __restrict__ Wt1,
                                                 ushort* __restrict__ Wt2) {
    int idx = blockIdx.x * 256 + threadIdx.x;
    const float* W = (idx < 16384) ? W1 : W2;
    ushort* O = (idx < 16384) ? Wt1 : Wt2;
    int i = idx & 16383;
    int k = i >> 7, n = i & 127;
    O[n * 128 + k] = f2bf(W[i]);
}

// ---------------- MFMA GEMM + attention coefficients ----------------
// Block 64x128, 4 waves (2M x 2N). feat OUT in head-sliced [8][N][16] bf16
// (for XCD-affine aggregation); el/er flat [N][8] f32 (32B rows for edge_weights).
// BF16IN path reads h1 in the sliced layout.
#define LDK 136
template <bool BF16IN>
__global__ __launch_bounds__(256) void gemm_attn_mfma(const void* __restrict__ in_,
                                                      const ushort* __restrict__ Wt,
                                                      const float* __restrict__ al,
                                                      const float* __restrict__ ar,
                                                      ushort* __restrict__ feat,
                                                      float* __restrict__ el,
                                                      float* __restrict__ er, int N) {
    __shared__ ushort sA[64 * LDK];
    int tid = threadIdx.x;
    int rowbase = blockIdx.x * 64;

    if (BF16IN) {
        const ushort* in = (const ushort*)in_;  // sliced [8][N][16]
#pragma unroll
        for (int i = 0; i < 4; ++i) {
            int idx8 = i * 256 + tid;
            int flat = idx8 * 8;
            int row = flat >> 7, col = flat & 127;   // col%16 in {0,8}
            int grow = rowbase + row;
            int hh = col >> 4, d = col & 15;
            uint4 v = make_uint4(0, 0, 0, 0);
            if (grow < N)
                v = *reinterpret_cast<const uint4*>(in + ((size_t)hh * N + grow) * 16 + d);
            *reinterpret_cast<uint4*>(&sA[row * LDK + col]) = v;
        }
    } else {
        const float* in = (const float*)in_;
#pragma unroll
        for (int i = 0; i < 8; ++i) {
            int idx4 = i * 256 + tid;
            int flat = idx4 * 4;
            int row = flat >> 7, col = flat & 127;
            int grow = rowbase + row;
            float4 v = make_float4(0.f, 0.f, 0.f, 0.f);
            if (grow < N) v = *reinterpret_cast<const float4*>(in + (size_t)grow * 128 + col);
            uint2 w;
            w.x = (unsigned int)f2bf(v.x) | ((unsigned int)f2bf(v.y) << 16);
            w.y = (unsigned int)f2bf(v.z) | ((unsigned int)f2bf(v.w) << 16);
            *reinterpret_cast<uint2*>(&sA[row * LDK + col]) = w;
        }
    }
    __syncthreads();

    int wid = tid >> 6;
    int lane = tid & 63;
    int wm = wid >> 1;
    int wn = wid & 1;
    int l15 = lane & 15;
    int lhi = lane >> 4;

    f32x4 acc[2][4] = {};
    const ushort* wb = Wt + (size_t)(wn * 64 + l15) * 128 + lhi * 8;
    const ushort* a0p = &sA[(wm * 32 + l15) * LDK + lhi * 8];
    const ushort* a1p = &sA[(wm * 32 + 16 + l15) * LDK + lhi * 8];

#pragma unroll
    for (int ks = 0; ks < 4; ++ks) {
        bf16x8 a0 = *reinterpret_cast<const bf16x8*>(a0p + ks * 32);
        bf16x8 a1 = *reinterpret_cast<const bf16x8*>(a1p + ks * 32);
#pragma unroll
        for (int ni = 0; ni < 4; ++ni) {
            bf16x8 b = *reinterpret_cast<const bf16x8*>(wb + ni * 16 * 128 + ks * 32);
            acc[0][ni] = __builtin_amdgcn_mfma_f32_16x16x32_bf16(a0, b, acc[0][ni], 0, 0, 0);
            acc[1][ni] = __builtin_amdgcn_mfma_f32_16x16x32_bf16(a1, b, acc[1][ni], 0, 0, 0);
        }
    }

#pragma unroll
    for (int ni = 0; ni < 4; ++ni) {
        int head = wn * 4 + ni;
        float alv = al[head * 16 + l15];
        float arv = ar[head * 16 + l15];
#pragma unroll
        for (int mi = 0; mi < 2; ++mi) {
#pragma unroll
            for (int reg = 0; reg < 4; ++reg) {
                int row = rowbase + wm * 32 + mi * 16 + lhi * 4 + reg;
                float v = acc[mi][ni][reg];
                float pl = v * alv;
                float pr = v * arv;
#pragma unroll
                for (int off = 8; off; off >>= 1) {
                    pl += __shfl_xor(pl, off);
                    pr += __shfl_xor(pr, off);
                }
                if (row < N) {
                    feat[((size_t)head * N + row) * 16 + l15] = f2bf(v);
                    if (l15 == 0) {
                        el[row * 8 + head] = pl;
                        er[row * 8 + head] = pr;
                    }
                }
            }
        }
    }
}

// ---------------- edge weights: w_t[h][j] = exp(leaky(el[src_j]+er[dst_j])) --------
// One thread per edge; el/er rows vector-loaded once (2x16B), all 8 head weights
// written. HEAD-MAJOR [8][E] layout is critical: [E][8] would be re-fetched by all
// 8 XCDs in the head-partitioned aggregate (8x w traffic); [8][E] gives each XCD a
// private contiguous 3.2MB stream. Writes: 8 stores, each coalesced across j.
__global__ __launch_bounds__(256) void edge_weights(const ushort* __restrict__ bucket,
                                                    const ushort* __restrict__ dst16,
                                                    const float* __restrict__ el,
                                                    const float* __restrict__ er,
                                                    float* __restrict__ w_t, int E) {
    int j = blockIdx.x * 256 + threadIdx.x;
    if (j >= E) return;
    int s = (int)bucket[j];
    int d = (int)dst16[j];
    float4 e0 = *reinterpret_cast<const float4*>(el + s * 8);
    float4 e1 = *reinterpret_cast<const float4*>(el + s * 8 + 4);
    float4 r0 = *reinterpret_cast<const float4*>(er + d * 8);
    float4 r1 = *reinterpret_cast<const float4*>(er + d * 8 + 4);
    float x[8] = {e0.x + r0.x, e0.y + r0.y, e0.z + r0.z, e0.w + r0.w,
                  e1.x + r1.x, e1.y + r1.y, e1.z + r1.z, e1.w + r1.w};
#pragma unroll
    for (int h = 0; h < 8; ++h) {
        float v = x[h];
        v = (v > 0.f) ? v : LEAKY * v;
        w_t[(size_t)h * E + j] = __expf(v);
    }
}

// ---------------- aggregation: head-sliced + XCD-affine + precomputed w ----------
// head = blockIdx&7 -> all blocks of head h share one XCD; its L2 sees only feat
// slice h (1.6MB) + w slice (3.2MB stream) -> gather L2-resident (rounds 10-12:
// FETCH 102->15MB). Wave = 8 edge-slots x 8 dim-pair lanes, ONE node at a time:
// no cross-node divergence; inner loop = {bucket, w, feat, 2fma} (w precomputed,
// round-13 win); epilogue = 3 values x 3 shfl_xor hops (3.6M bpermutes total,
// ~3us -- vs round-10's 10M disaster).
__global__ __launch_bounds__(256) void aggregate(const ushort* __restrict__ feat_s, // [8][N][16]
                                                 const float* __restrict__ w_t,     // [8][E]
                                                 const int* __restrict__ rowstart,
                                                 const ushort* __restrict__ bucket,
                                                 const float* __restrict__ bias,    // [8][16]
                                                 ushort* __restrict__ out_s,        // [8][N][16]
                                                 int N, int E, int do_relu) {
    int h = blockIdx.x & 7;
    int g = blockIdx.x >> 3;
    int wv = threadIdx.x >> 6;
    int lane = threadIdx.x & 63;
    int e8 = lane >> 3;  // edge slot 0..7
    int dl = lane & 7;   // dim-pair lane (owns dims 2dl, 2dl+1)

    const unsigned int* fp = reinterpret_cast<const unsigned int*>(feat_s) + (size_t)h * N * 8 + dl;
    unsigned int* op = reinterpret_cast<unsigned int*>(out_s) + (size_t)h * N * 8 + dl;
    const float* wh = w_t + (size_t)h * E;
    float2 bv = *reinterpret_cast<const float2*>(bias + h * 16 + dl * 2);

    int n0 = (g * 4 + wv) * 16;  // 16 nodes per wave
    int n1 = min(n0 + 16, N);

    for (int n = n0; n < n1; ++n) {
        int beg = rowstart[n];
        int end = rowstart[n + 1];
        float lsum = 0.f, ax = 0.f, ay = 0.f;

        for (int base = beg; base < end; base += 8) {
            int j = base + e8;
            bool vld = j < end;
            int jj = vld ? j : beg;
            int s = (int)bucket[jj];          // 16B coalesced
            float wgt = vld ? wh[jj] : 0.f;   // 32B coalesced (XCD-private stream)
            unsigned int u = fp[(size_t)s * 8];  // 8 lanes = one 32B segment (L2-res)
            lsum += wgt;
            ax = fmaf(wgt, bflo(u), ax);
            ay = fmaf(wgt, bfhi(u), ay);
        }

        // reduce over the 8 edge-slots (masks 8,16,32); dl groups stay independent
        ax += __shfl_xor(ax, 8);  ay += __shfl_xor(ay, 8);  lsum += __shfl_xor(lsum, 8);
        ax += __shfl_xor(ax, 16); ay += __shfl_xor(ay, 16); lsum += __shfl_xor(lsum, 16);
        ax += __shfl_xor(ax, 32); ay += __shfl_xor(ay, 32); lsum += __shfl_xor(lsum, 32);

        float inv = (end > beg) ? 1.0f / lsum : 0.0f;
        float o0 = fmaf(ax, inv, bv.x);
        float o1 = fmaf(ay, inv, bv.y);
        if (do_relu) {
            o0 = fmaxf(o0, 0.f);
            o1 = fmaxf(o1, 0.f);
        }
        if (lane < 8)  // e8 == 0 lanes write the node's 32B
            op[(size_t)n * 8] = (unsigned int)f2bf(o0) | ((unsigned int)f2bf(o1) << 16);
    }
}

// ---------------- readout (h2 in sliced layout) ----------------
__global__ __launch_bounds__(256) void mean_reduce(const ushort* __restrict__ h,
                                                   float* __restrict__ meanbuf, int N) {
    int c = threadIdx.x & 127;
    int hh = c >> 4, d = c & 15;
    int rbase = blockIdx.x * 2 + (threadIdx.x >> 7);
    float s = 0.0f;
    for (int r = rbase; r < N; r += gridDim.x * 2)
        s += __uint_as_float((unsigned int)h[((size_t)hh * N + r) * 16 + d] << 16);
    atomicAdd(&meanbuf[c], s);
}

__global__ __launch_bounds__(64) void classifier(const float* __restrict__ meanbuf,
                                                 const float* __restrict__ Wc,
                                                 const float* __restrict__ bc,
                                                 float* __restrict__ outp, float invN) {
    int j = threadIdx.x;
    if (j < 10) {
        float s = 0.0f;
        for (int k = 0; k < 128; ++k) s += meanbuf[k] * invN * Wc[k * 10 + j];
        outp[j] = s + bc[j];
    }
}

// ---------------- launch ----------------

extern "C" void kernel_launch(void* const* d_in, const int* in_sizes, int n_in,
                              void* d_out, int out_size, void* d_ws, size_t ws_size,
                              hipStream_t stream) {
    const float* x   = (const float*)d_in[0];
    const int*   src = (const int*)d_in[1];
    const int*   dst = (const int*)d_in[2];
    const float* W1  = (const float*)d_in[3];
    const float* al1 = (const float*)d_in[4];
    const float* ar1 = (const float*)d_in[5];
    const float* b1  = (const float*)d_in[6];
    const float* W2  = (const float*)d_in[7];
    const float* al2 = (const float*)d_in[8];
    const float* ar2 = (const float*)d_in[9];
    const float* b2  = (const float*)d_in[10];
    const float* Wc  = (const float*)d_in[11];
    const float* bc  = (const float*)d_in[12];

    int N = in_sizes[0] / 128;
    int E = in_sizes[1];
    int NB = (N + (1 << BINB) - 1) >> BINB;

    size_t off = 0;
    auto alloc = [&](size_t bytes) -> void* {
        void* p = (char*)d_ws + off;
        off += (bytes + 255) & ~size_t(255);
        return p;
    };
    int*   bin_cnt    = (int*)alloc(sizeof(int) * NB);
    int*   binStart   = (int*)alloc(sizeof(int) * (NB + 1));
    int*   bin_cursor = (int*)alloc(sizeof(int) * NB);
    int*   rowstart   = (int*)alloc(sizeof(int) * (N + 1));
    unsigned int* coarse = (unsigned int*)alloc(sizeof(unsigned int) * E);
    ushort* bucket  = (ushort*)alloc(sizeof(ushort) * E);
    ushort* dst16   = (ushort*)alloc(sizeof(ushort) * E);
    float* wbuf     = (float*)alloc(sizeof(float) * (size_t)E * 8);
    ushort* feat    = (ushort*)alloc(sizeof(ushort) * (size_t)N * 128);
    float* el       = (float*)alloc(sizeof(float) * N * 8);
    float* er       = (float*)alloc(sizeof(float) * N * 8);
    ushort* h1      = (ushort*)alloc(sizeof(ushort) * (size_t)N * 128);
    ushort* h2      = (ushort*)alloc(sizeof(ushort) * (size_t)N * 128);
    float* meanbuf  = (float*)alloc(sizeof(float) * 128);
    ushort* Wt1     = (ushort*)alloc(sizeof(ushort) * 128 * 128);
    ushort* Wt2     = (ushort*)alloc(sizeof(ushort) * 128 * 128);

    hipMemsetAsync(bin_cnt, 0, sizeof(int) * NB, stream);
    hipMemsetAsync(meanbuf, 0, sizeof(float) * 128, stream);

    int GB = ceil_div(E, TILE);
    int AGG = ceil_div(N, 64) * 8;  // 64 nodes/block x 8 heads (head = blockIdx&7)

    bin_count<<<GB, 256, 0, stream>>>(dst, bin_cnt, E, NB);
    bin_scan<<<1, 256, 0, stream>>>(bin_cnt, binStart, bin_cursor, rowstart, NB, N, E);
    bin_scatter<<<GB, 256, 0, stream>>>(src, dst, bin_cursor, coarse, E);
    fine_csr<<<NB, 256, 0, stream>>>(coarse, binStart, rowstart, bucket, dst16, N);
    convert_w<<<128, 256, 0, stream>>>(W1, W2, Wt1, Wt2);

    // layer 1 (f32 input)
    gemm_attn_mfma<false><<<ceil_div(N, 64), 256, 0, stream>>>(x, Wt1, al1, ar1, feat, el, er, N);
    edge_weights<<<ceil_div(E, 256), 256, 0, stream>>>(bucket, dst16, el, er, wbuf, E);
    aggregate<<<AGG, 256, 0, stream>>>(feat, wbuf, rowstart, bucket, b1, h1, N, E, 1);
    // layer 2 (sliced bf16 input)
    gemm_attn_mfma<true><<<ceil_div(N, 64), 256, 0, stream>>>(h1, Wt2, al2, ar2, feat, el, er, N);
    edge_weights<<<ceil_div(E, 256), 256, 0, stream>>>(bucket, dst16, el, er, wbuf, E);
    aggregate<<<AGG, 256, 0, stream>>>(feat, wbuf, rowstart, bucket, b2, h2, N, E, 0);
    // readout
    mean_reduce<<<256, 256, 0, stream>>>(h2, meanbuf, N);
    classifier<<<1, 64, 0, stream>>>(meanbuf, Wc, bc, (float*)d_out, 1.0f / (float)N);
}

// Round 15
// 298.187 us; speedup vs baseline: 1.2146x; 1.2146x over previous
//
#include <hip/hip_runtime.h>
#include <hip/hip_bf16.h>

#define LEAKY 0.2f
#define BINB 8          // 256 nodes per bin (requires N <= 65536 for u16 packing)
#define TILE 2048       // edges per block in binning kernels
#define CAP 8192        // LDS bucket-segment capacity per bin (avg ~4081)

static inline int ceil_div(int a, int b) { return (a + b - 1) / b; }

typedef __bf16 bf16x8 __attribute__((ext_vector_type(8)));
typedef float f32x4 __attribute__((ext_vector_type(4)));

// f32 -> bf16 bits, round-to-nearest-even
__device__ __forceinline__ ushort f2bf(float f) {
    unsigned int x = __float_as_uint(f);
    unsigned int r = (x + 0x7fffu + ((x >> 16) & 1u)) >> 16;
    return (ushort)r;
}
__device__ __forceinline__ float bflo(unsigned int u) { return __uint_as_float(u << 16); }
__device__ __forceinline__ float bfhi(unsigned int u) { return __uint_as_float(u & 0xffff0000u); }

// ---------------- CSR build (two-level, coalesced writes) ----------------
// Round-4 lesson: one-pass random 4B scatter = 17x HBM write amplification.

__global__ __launch_bounds__(256) void bin_count(const int* __restrict__ dst,
                                                 int* __restrict__ bin_cnt, int E, int NB) {
    __shared__ int h[256];
    int t = threadIdx.x;
    h[t] = 0;
    __syncthreads();
    int base = blockIdx.x * TILE;
#pragma unroll
    for (int j = 0; j < TILE / 256; ++j) {
        int i = base + j * 256 + t;
        if (i < E) atomicAdd(&h[dst[i] >> BINB], 1);
    }
    __syncthreads();
    if (t < NB && h[t]) atomicAdd(&bin_cnt[t], h[t]);
}

__global__ __launch_bounds__(256) void bin_scan(const int* __restrict__ bin_cnt,
                                                int* __restrict__ binStart,
                                                int* __restrict__ bin_cursor,
                                                int* __restrict__ rowstart,
                                                int NB, int N, int E) {
    __shared__ int s[256];
    int t = threadIdx.x;
    int v = (t < NB) ? bin_cnt[t] : 0;
    s[t] = v;
    __syncthreads();
    for (int off = 1; off < 256; off <<= 1) {
        int x = (t >= off) ? s[t - off] : 0;
        __syncthreads();
        s[t] += x;
        __syncthreads();
    }
    int excl = s[t] - v;
    if (t < NB) {
        binStart[t] = excl;
        bin_cursor[t] = excl;
        if (t == NB - 1) binStart[NB] = excl + v;
    }
    if (t == 0) rowstart[N] = E;
}

__global__ __launch_bounds__(256) void bin_scatter(const int* __restrict__ src,
                                                   const int* __restrict__ dst,
                                                   int* __restrict__ bin_cursor,
                                                   unsigned int* __restrict__ coarse, int E) {
    __shared__ int hist[256], scn[256], gbase[256], lcur[256];
    __shared__ unsigned int outp[TILE];
    __shared__ int gidx[TILE];
    int t = threadIdx.x;
    hist[t] = 0;
    __syncthreads();
    int base = blockIdx.x * TILE;
    int dloc[TILE / 256];
#pragma unroll
    for (int j = 0; j < TILE / 256; ++j) {
        int i = base + j * 256 + t;
        int d = (i < E) ? dst[i] : -1;
        dloc[j] = d;
        if (d >= 0) atomicAdd(&hist[d >> BINB], 1);
    }
    __syncthreads();
    int hv = hist[t];
    scn[t] = hv;
    __syncthreads();
    for (int off = 1; off < 256; off <<= 1) {
        int x = (t >= off) ? scn[t - off] : 0;
        __syncthreads();
        scn[t] += x;
        __syncthreads();
    }
    int excl = scn[t] - hv;
    if (hv > 0) gbase[t] = atomicAdd(&bin_cursor[t], hv);
    lcur[t] = excl;
    scn[t] = excl;
    __syncthreads();
#pragma unroll
    for (int j = 0; j < TILE / 256; ++j) {
        int i = base + j * 256 + t;
        int d = dloc[j];
        if (d >= 0) {
            int b = d >> BINB;
            int pos = atomicAdd(&lcur[b], 1);
            outp[pos] = (unsigned int)src[i] | ((unsigned int)(d & ((1 << BINB) - 1)) << 16);
            gidx[pos] = gbase[b] + (pos - scn[b]);
        }
    }
    __syncthreads();
    int cnt = min(TILE, E - base);
    for (int j = t; j < cnt; j += 256) coarse[gidx[j]] = outp[j];
}

// Also emits dst16[j] = global dst node of CSR slot j (needed by edge_weights).
__global__ __launch_bounds__(256) void fine_csr(const unsigned int* __restrict__ coarse,
                                                const int* __restrict__ binStart,
                                                int* __restrict__ rowstart,
                                                ushort* __restrict__ bucket,
                                                ushort* __restrict__ dst16, int N) {
    __shared__ int hist[256], scn[256], cur[256];
    __shared__ ushort sb[CAP];
    __shared__ ushort db[CAP];
    int b = blockIdx.x, t = threadIdx.x;
    int e0 = binStart[b], e1 = binStart[b + 1];
    int cnt = e1 - e0;
    hist[t] = 0;
    __syncthreads();
    for (int j = e0 + t; j < e1; j += 256) atomicAdd(&hist[coarse[j] >> 16], 1);
    __syncthreads();
    int hv = hist[t];
    scn[t] = hv;
    __syncthreads();
    for (int off = 1; off < 256; off <<= 1) {
        int x = (t >= off) ? scn[t - off] : 0;
        __syncthreads();
        scn[t] += x;
        __syncthreads();
    }
    int excl = scn[t] - hv;
    int n = (b << BINB) + t;
    if (n < N) rowstart[n] = e0 + excl;
    cur[t] = excl;
    __syncthreads();
    bool fit = (cnt <= CAP);
    for (int j = e0 + t; j < e1; j += 256) {
        unsigned int p = coarse[j];
        int dl = p >> 16;
        int pos = atomicAdd(&cur[dl], 1);
        ushort sv = (ushort)(p & 0xffffu);
        ushort dv = (ushort)((b << BINB) | dl);
        if (fit) {
            sb[pos] = sv;
            db[pos] = dv;
        } else {
            bucket[e0 + pos] = sv;
            dst16[e0 + pos] = dv;
        }
    }
    __syncthreads();
    if (fit) {
        for (int j = t; j < cnt; j += 256) {
            bucket[e0 + j] = sb[j];
            dst16[e0 + j] = db[j];
        }
    }
}

// ---------------- W convert: Wt[n][k] = bf16(W[k][n]) ----------------
__global__ __launch_bounds__(256) void convert_w(const float* __restrict__ W1,
                                                 const float* __restrict__ W2,
                                                 ushort* __restrict__ Wt1,
                                                 ushort* __restrict__ Wt2) {
    int idx = blockIdx.x * 256 + threadIdx.x;
    const float* W = (idx < 16384) ? W1 : W2;
    ushort* O = (idx < 16384) ? Wt1 : Wt2;
    int i = idx & 16383;
    int k = i >> 7, n = i & 127;
    O[n * 128 + k] = f2bf(W[i]);
}

// ---------------- MFMA GEMM + attention coefficients (flat layouts) ----------------
// Block 64x128, 4 waves (2M x 2N). feat [N][128] bf16; el/er [N][8] f32.
#define LDK 136
template <bool BF16IN>
__global__ __launch_bounds__(256) void gemm_attn_mfma(const void* __restrict__ in_,
                                                      const ushort* __restrict__ Wt,
                                                      const float* __restrict__ al,
                                                      const float* __restrict__ ar,
                                                      ushort* __restrict__ feat,
                                                      float* __restrict__ el,
                                                      float* __restrict__ er, int N) {
    __shared__ ushort sA[64 * LDK];
    int tid = threadIdx.x;
    int rowbase = blockIdx.x * 64;

    if (BF16IN) {
        const ushort* in = (const ushort*)in_;
#pragma unroll
        for (int i = 0; i < 4; ++i) {
            int idx8 = i * 256 + tid;
            int flat = idx8 * 8;
            int row = flat >> 7, col = flat & 127;
            int grow = rowbase + row;
            uint4 v = make_uint4(0, 0, 0, 0);
            if (grow < N) v = *reinterpret_cast<const uint4*>(in + (size_t)grow * 128 + col);
            *reinterpret_cast<uint4*>(&sA[row * LDK + col]) = v;
        }
    } else {
        const float* in = (const float*)in_;
#pragma unroll
        for (int i = 0; i < 8; ++i) {
            int idx4 = i * 256 + tid;
            int flat = idx4 * 4;
            int row = flat >> 7, col = flat & 127;
            int grow = rowbase + row;
            float4 v = make_float4(0.f, 0.f, 0.f, 0.f);
            if (grow < N) v = *reinterpret_cast<const float4*>(in + (size_t)grow * 128 + col);
            uint2 w;
            w.x = (unsigned int)f2bf(v.x) | ((unsigned int)f2bf(v.y) << 16);
            w.y = (unsigned int)f2bf(v.z) | ((unsigned int)f2bf(v.w) << 16);
            *reinterpret_cast<uint2*>(&sA[row * LDK + col]) = w;
        }
    }
    __syncthreads();

    int wid = tid >> 6;
    int lane = tid & 63;
    int wm = wid >> 1;
    int wn = wid & 1;
    int l15 = lane & 15;
    int lhi = lane >> 4;

    f32x4 acc[2][4] = {};
    const ushort* wb = Wt + (size_t)(wn * 64 + l15) * 128 + lhi * 8;
    const ushort* a0p = &sA[(wm * 32 + l15) * LDK + lhi * 8];
    const ushort* a1p = &sA[(wm * 32 + 16 + l15) * LDK + lhi * 8];

#pragma unroll
    for (int ks = 0; ks < 4; ++ks) {
        bf16x8 a0 = *reinterpret_cast<const bf16x8*>(a0p + ks * 32);
        bf16x8 a1 = *reinterpret_cast<const bf16x8*>(a1p + ks * 32);
#pragma unroll
        for (int ni = 0; ni < 4; ++ni) {
            bf16x8 b = *reinterpret_cast<const bf16x8*>(wb + ni * 16 * 128 + ks * 32);
            acc[0][ni] = __builtin_amdgcn_mfma_f32_16x16x32_bf16(a0, b, acc[0][ni], 0, 0, 0);
            acc[1][ni] = __builtin_amdgcn_mfma_f32_16x16x32_bf16(a1, b, acc[1][ni], 0, 0, 0);
        }
    }

#pragma unroll
    for (int ni = 0; ni < 4; ++ni) {
        int head = wn * 4 + ni;
        float alv = al[head * 16 + l15];
        float arv = ar[head * 16 + l15];
#pragma unroll
        for (int mi = 0; mi < 2; ++mi) {
#pragma unroll
            for (int reg = 0; reg < 4; ++reg) {
                int row = rowbase + wm * 32 + mi * 16 + lhi * 4 + reg;
                float v = acc[mi][ni][reg];
                float pl = v * alv;
                float pr = v * arv;
#pragma unroll
                for (int off = 8; off; off >>= 1) {
                    pl += __shfl_xor(pl, off);
                    pr += __shfl_xor(pr, off);
                }
                if (row < N) {
                    feat[(size_t)row * 128 + head * 16 + l15] = f2bf(v);
                    if (l15 == 0) {
                        el[row * 8 + head] = pl;
                        er[row * 8 + head] = pr;
                    }
                }
            }
        }
    }
}

// ---------------- edge weights: w[j][h] = bf16(exp(leaky(el[src]+er[dst]))) --------
// Edge-parallel, fully coalesced, zero divergence. bf16 storage halves both the
// write here and the read in aggregate (precision: ~0.4% on weights, and
// alpha = w/sum(w) self-cancels the common scale; absmax headroom 8.5x).
__global__ __launch_bounds__(256) void edge_weights(const ushort* __restrict__ bucket,
                                                    const ushort* __restrict__ dst16,
                                                    const float* __restrict__ el,
                                                    const float* __restrict__ er,
                                                    ushort* __restrict__ w, int E) {
    int tid0 = blockIdx.x * 256 + threadIdx.x;
    int h = tid0 & 7;
    int stride = (gridDim.x * 256) >> 3;
    for (int j = tid0 >> 3; j < E; j += stride) {
        int s = (int)bucket[j];   // 8 threads share j -> broadcast
        int d = (int)dst16[j];
        float x = el[s * 8 + h] + er[d * 8 + h];   // 32B contiguous per edge
        x = (x > 0.f) ? x : LEAKY * x;
        w[(size_t)j * 8 + h] = f2bf(__expf(x));    // coalesced 128B per 8 edges
    }
}

// ---------------- per-dst-node aggregation (flat, all heads per walk) ----------------
// Round-13-proven structure (39.6us): one wave per node; lane owns dims
// 2*lane,2*lane+1 (head = lane>>3); each edge visited ONCE serving all 8 heads;
// weights precomputed -> inner loop = shfl + 2 loads + 3 VALU. Round-14 lesson:
// do NOT head-partition this walk -- (node,head) waves cost 2.3x instruction
// efficiency + 9 shfl-hops/task; the 8x XCD feat re-fetch (~91MB) is cheaper.
// Batch-16 ILP: 32 loads in flight to push gather BW toward 3TB/s.
__global__ __launch_bounds__(256) void aggregate(const ushort* __restrict__ feat,
                                                 const ushort* __restrict__ w,   // [E][8] bf16
                                                 const int* __restrict__ rowstart,
                                                 const ushort* __restrict__ bucket,
                                                 const float* __restrict__ bias,
                                                 ushort* __restrict__ out,
                                                 int N, int do_relu) {
    int wid = (blockIdx.x * 256 + threadIdx.x) >> 6;
    int lane = threadIdx.x & 63;
    if (wid >= N) return;
    int h = lane >> 3;
    int beg = rowstart[wid];
    int end = rowstart[wid + 1];

    const unsigned int* fp = reinterpret_cast<const unsigned int*>(feat) + lane;
    const ushort* wh = w + h;

    float lsum = 0.f, ax = 0.f, ay = 0.f;

    for (int base = beg; base < end; base += 64) {
        int cnt = min(end - base, 64);
        int myedge = base + lane;
        int sv = (myedge < end) ? (int)bucket[myedge] : 0;  // coalesced 128B per 64 edges
        int k = 0;
        for (; k + 16 <= cnt; k += 16) {
            int ss[16];
            float ww[16];
            unsigned int uu[16];
#pragma unroll
            for (int q = 0; q < 16; ++q) ss[q] = __shfl(sv, k + q);
#pragma unroll
            for (int q = 0; q < 16; ++q) ww[q] = bflo((unsigned int)wh[(size_t)(base + k + q) * 8]);
#pragma unroll
            for (int q = 0; q < 16; ++q) uu[q] = fp[(size_t)ss[q] * 64];  // 256B row
#pragma unroll
            for (int q = 0; q < 16; ++q) {
                lsum += ww[q];
                ax = fmaf(ww[q], bflo(uu[q]), ax);
                ay = fmaf(ww[q], bfhi(uu[q]), ay);
            }
        }
        for (; k + 8 <= cnt; k += 8) {
            int ss[8];
            float ww[8];
            unsigned int uu[8];
#pragma unroll
            for (int q = 0; q < 8; ++q) ss[q] = __shfl(sv, k + q);
#pragma unroll
            for (int q = 0; q < 8; ++q) ww[q] = bflo((unsigned int)wh[(size_t)(base + k + q) * 8]);
#pragma unroll
            for (int q = 0; q < 8; ++q) uu[q] = fp[(size_t)ss[q] * 64];
#pragma unroll
            for (int q = 0; q < 8; ++q) {
                lsum += ww[q];
                ax = fmaf(ww[q], bflo(uu[q]), ax);
                ay = fmaf(ww[q], bfhi(uu[q]), ay);
            }
        }
        for (; k < cnt; ++k) {
            int s = __shfl(sv, k);
            float wv = bflo((unsigned int)wh[(size_t)(base + k) * 8]);
            unsigned int u = fp[(size_t)s * 64];
            lsum += wv;
            ax = fmaf(wv, bflo(u), ax);
            ay = fmaf(wv, bfhi(u), ay);
        }
    }

    float inv = (end > beg) ? 1.0f / lsum : 0.0f;
    int c = lane * 2;
    float2 bv = *reinterpret_cast<const float2*>(bias + c);
    float ox = fmaf(ax, inv, bv.x);
    float oy = fmaf(ay, inv, bv.y);
    if (do_relu) {
        ox = fmaxf(ox, 0.f);
        oy = fmaxf(oy, 0.f);
    }
    reinterpret_cast<unsigned int*>(out)[(size_t)wid * 64 + lane] =
        (unsigned int)f2bf(ox) | ((unsigned int)f2bf(oy) << 16);
}

// ---------------- readout (flat bf16) ----------------
__global__ __launch_bounds__(256) void mean_reduce(const ushort* __restrict__ h,
                                                   float* __restrict__ meanbuf, int N) {
    int c = threadIdx.x & 127;
    int rbase = blockIdx.x * 2 + (threadIdx.x >> 7);
    float s = 0.0f;
    for (int r = rbase; r < N; r += gridDim.x * 2)
        s += __uint_as_float((unsigned int)h[(size_t)r * 128 + c] << 16);
    atomicAdd(&meanbuf[c], s);
}

__global__ __launch_bounds__(64) void classifier(const float* __restrict__ meanbuf,
                                                 const float* __restrict__ Wc,
                                                 const float* __restrict__ bc,
                                                 float* __restrict__ outp, float invN) {
    int j = threadIdx.x;
    if (j < 10) {
        float s = 0.0f;
        for (int k = 0; k < 128; ++k) s += meanbuf[k] * invN * Wc[k * 10 + j];
        outp[j] = s + bc[j];
    }
}

// ---------------- launch ----------------

extern "C" void kernel_launch(void* const* d_in, const int* in_sizes, int n_in,
                              void* d_out, int out_size, void* d_ws, size_t ws_size,
                              hipStream_t stream) {
    const float* x   = (const float*)d_in[0];
    const int*   src = (const int*)d_in[1];
    const int*   dst = (const int*)d_in[2];
    const float* W1  = (const float*)d_in[3];
    const float* al1 = (const float*)d_in[4];
    const float* ar1 = (const float*)d_in[5];
    const float* b1  = (const float*)d_in[6];
    const float* W2  = (const float*)d_in[7];
    const float* al2 = (const float*)d_in[8];
    const float* ar2 = (const float*)d_in[9];
    const float* b2  = (const float*)d_in[10];
    const float* Wc  = (const float*)d_in[11];
    const float* bc  = (const float*)d_in[12];

    int N = in_sizes[0] / 128;
    int E = in_sizes[1];
    int NB = (N + (1 << BINB) - 1) >> BINB;

    size_t off = 0;
    auto alloc = [&](size_t bytes) -> void* {
        void* p = (char*)d_ws + off;
        off += (bytes + 255) & ~size_t(255);
        return p;
    };
    int*   bin_cnt    = (int*)alloc(sizeof(int) * NB);
    int*   binStart   = (int*)alloc(sizeof(int) * (NB + 1));
    int*   bin_cursor = (int*)alloc(sizeof(int) * NB);
    int*   rowstart   = (int*)alloc(sizeof(int) * (N + 1));
    unsigned int* coarse = (unsigned int*)alloc(sizeof(unsigned int) * E);
    ushort* bucket  = (ushort*)alloc(sizeof(ushort) * E);
    ushort* dst16   = (ushort*)alloc(sizeof(ushort) * E);
    ushort* wbuf    = (ushort*)alloc(sizeof(ushort) * (size_t)E * 8);
    ushort* feat    = (ushort*)alloc(sizeof(ushort) * (size_t)N * 128);
    float* el       = (float*)alloc(sizeof(float) * N * 8);
    float* er       = (float*)alloc(sizeof(float) * N * 8);
    ushort* h1      = (ushort*)alloc(sizeof(ushort) * (size_t)N * 128);
    ushort* h2      = (ushort*)alloc(sizeof(ushort) * (size_t)N * 128);
    float* meanbuf  = (float*)alloc(sizeof(float) * 128);
    ushort* Wt1     = (ushort*)alloc(sizeof(ushort) * 128 * 128);
    ushort* Wt2     = (ushort*)alloc(sizeof(ushort) * 128 * 128);

    hipMemsetAsync(bin_cnt, 0, sizeof(int) * NB, stream);
    hipMemsetAsync(meanbuf, 0, sizeof(float) * 128, stream);

    int GB = ceil_div(E, TILE);

    bin_count<<<GB, 256, 0, stream>>>(dst, bin_cnt, E, NB);
    bin_scan<<<1, 256, 0, stream>>>(bin_cnt, binStart, bin_cursor, rowstart, NB, N, E);
    bin_scatter<<<GB, 256, 0, stream>>>(src, dst, bin_cursor, coarse, E);
    fine_csr<<<NB, 256, 0, stream>>>(coarse, binStart, rowstart, bucket, dst16, N);
    convert_w<<<128, 256, 0, stream>>>(W1, W2, Wt1, Wt2);

    // layer 1 (f32 input)
    gemm_attn_mfma<false><<<ceil_div(N, 64), 256, 0, stream>>>(x, Wt1, al1, ar1, feat, el, er, N);
    edge_weights<<<2048, 256, 0, stream>>>(bucket, dst16, el, er, wbuf, E);
    aggregate<<<ceil_div(N * 64, 256), 256, 0, stream>>>(feat, wbuf, rowstart, bucket, b1, h1, N, 1);
    // layer 2 (flat bf16 input)
    gemm_attn_mfma<true><<<ceil_div(N, 64), 256, 0, stream>>>(h1, Wt2, al2, ar2, feat, el, er, N);
    edge_weights<<<2048, 256, 0, stream>>>(bucket, dst16, el, er, wbuf, E);
    aggregate<<<ceil_div(N * 64, 256), 256, 0, stream>>>(feat, wbuf, rowstart, bucket, b2, h2, N, 0);
    // readout
    mean_reduce<<<256, 256, 0, stream>>>(h2, meanbuf, N);
    classifier<<<1, 64, 0, stream>>>(meanbuf, Wc, bc, (float*)d_out, 1.0f / (float)N);
}

// Round 16
// 232.344 us; speedup vs baseline: 1.5588x; 1.2834x over previous
//
#include <hip/hip_runtime.h>
#include <hip/hip_bf16.h>

#define LEAKY 0.2f
#define BINB 8          // 256 nodes per bin (requires N <= 65536 for u16 packing)
#define TILE 2048       // edges per block in binning kernels
#define CAP 8192        // LDS bucket-segment capacity per bin (avg ~4081)

static inline int ceil_div(int a, int b) { return (a + b - 1) / b; }

typedef __bf16 bf16x8 __attribute__((ext_vector_type(8)));
typedef float f32x4 __attribute__((ext_vector_type(4)));

// f32 -> bf16 bits, round-to-nearest-even
__device__ __forceinline__ ushort f2bf(float f) {
    unsigned int x = __float_as_uint(f);
    unsigned int r = (x + 0x7fffu + ((x >> 16) & 1u)) >> 16;
    return (ushort)r;
}
__device__ __forceinline__ float bflo(unsigned int u) { return __uint_as_float(u << 16); }
__device__ __forceinline__ float bfhi(unsigned int u) { return __uint_as_float(u & 0xffff0000u); }

// ---------------- CSR build (two-level, coalesced writes) ----------------
// Round-4 lesson: one-pass random 4B scatter = 17x HBM write amplification.

__global__ __launch_bounds__(256) void bin_count(const int* __restrict__ dst,
                                                 int* __restrict__ bin_cnt, int E, int NB) {
    __shared__ int h[256];
    int t = threadIdx.x;
    h[t] = 0;
    __syncthreads();
    int base = blockIdx.x * TILE;
#pragma unroll
    for (int j = 0; j < TILE / 256; ++j) {
        int i = base + j * 256 + t;
        if (i < E) atomicAdd(&h[dst[i] >> BINB], 1);
    }
    __syncthreads();
    if (t < NB && h[t]) atomicAdd(&bin_cnt[t], h[t]);
}

__global__ __launch_bounds__(256) void bin_scan(const int* __restrict__ bin_cnt,
                                                int* __restrict__ binStart,
                                                int* __restrict__ bin_cursor,
                                                int* __restrict__ rowstart,
                                                int NB, int N, int E) {
    __shared__ int s[256];
    int t = threadIdx.x;
    int v = (t < NB) ? bin_cnt[t] : 0;
    s[t] = v;
    __syncthreads();
    for (int off = 1; off < 256; off <<= 1) {
        int x = (t >= off) ? s[t - off] : 0;
        __syncthreads();
        s[t] += x;
        __syncthreads();
    }
    int excl = s[t] - v;
    if (t < NB) {
        binStart[t] = excl;
        bin_cursor[t] = excl;
        if (t == NB - 1) binStart[NB] = excl + v;
    }
    if (t == 0) rowstart[N] = E;
}

__global__ __launch_bounds__(256) void bin_scatter(const int* __restrict__ src,
                                                   const int* __restrict__ dst,
                                                   int* __restrict__ bin_cursor,
                                                   unsigned int* __restrict__ coarse, int E) {
    __shared__ int hist[256], scn[256], gbase[256], lcur[256];
    __shared__ unsigned int outp[TILE];
    __shared__ int gidx[TILE];
    int t = threadIdx.x;
    hist[t] = 0;
    __syncthreads();
    int base = blockIdx.x * TILE;
    int dloc[TILE / 256];
#pragma unroll
    for (int j = 0; j < TILE / 256; ++j) {
        int i = base + j * 256 + t;
        int d = (i < E) ? dst[i] : -1;
        dloc[j] = d;
        if (d >= 0) atomicAdd(&hist[d >> BINB], 1);
    }
    __syncthreads();
    int hv = hist[t];
    scn[t] = hv;
    __syncthreads();
    for (int off = 1; off < 256; off <<= 1) {
        int x = (t >= off) ? scn[t - off] : 0;
        __syncthreads();
        scn[t] += x;
        __syncthreads();
    }
    int excl = scn[t] - hv;
    if (hv > 0) gbase[t] = atomicAdd(&bin_cursor[t], hv);
    lcur[t] = excl;
    scn[t] = excl;
    __syncthreads();
#pragma unroll
    for (int j = 0; j < TILE / 256; ++j) {
        int i = base + j * 256 + t;
        int d = dloc[j];
        if (d >= 0) {
            int b = d >> BINB;
            int pos = atomicAdd(&lcur[b], 1);
            outp[pos] = (unsigned int)src[i] | ((unsigned int)(d & ((1 << BINB) - 1)) << 16);
            gidx[pos] = gbase[b] + (pos - scn[b]);
        }
    }
    __syncthreads();
    int cnt = min(TILE, E - base);
    for (int j = t; j < cnt; j += 256) coarse[gidx[j]] = outp[j];
}

// Also emits dst16[j] = global dst node of CSR slot j (needed by edge_weights).
__global__ __launch_bounds__(256) void fine_csr(const unsigned int* __restrict__ coarse,
                                                const int* __restrict__ binStart,
                                                int* __restrict__ rowstart,
                                                ushort* __restrict__ bucket,
                                                ushort* __restrict__ dst16, int N) {
    __shared__ int hist[256], scn[256], cur[256];
    __shared__ ushort sb[CAP];
    __shared__ ushort db[CAP];
    int b = blockIdx.x, t = threadIdx.x;
    int e0 = binStart[b], e1 = binStart[b + 1];
    int cnt = e1 - e0;
    hist[t] = 0;
    __syncthreads();
    for (int j = e0 + t; j < e1; j += 256) atomicAdd(&hist[coarse[j] >> 16], 1);
    __syncthreads();
    int hv = hist[t];
    scn[t] = hv;
    __syncthreads();
    for (int off = 1; off < 256; off <<= 1) {
        int x = (t >= off) ? scn[t - off] : 0;
        __syncthreads();
        scn[t] += x;
        __syncthreads();
    }
    int excl = scn[t] - hv;
    int n = (b << BINB) + t;
    if (n < N) rowstart[n] = e0 + excl;
    cur[t] = excl;
    __syncthreads();
    bool fit = (cnt <= CAP);
    for (int j = e0 + t; j < e1; j += 256) {
        unsigned int p = coarse[j];
        int dl = p >> 16;
        int pos = atomicAdd(&cur[dl], 1);
        ushort sv = (ushort)(p & 0xffffu);
        ushort dv = (ushort)((b << BINB) | dl);
        if (fit) {
            sb[pos] = sv;
            db[pos] = dv;
        } else {
            bucket[e0 + pos] = sv;
            dst16[e0 + pos] = dv;
        }
    }
    __syncthreads();
    if (fit) {
        for (int j = t; j < cnt; j += 256) {
            bucket[e0 + j] = sb[j];
            dst16[e0 + j] = db[j];
        }
    }
}

// ---------------- W convert: Wt[n][k] = bf16(W[k][n]) ----------------
__global__ __launch_bounds__(256) void convert_w(const float* __restrict__ W1,
                                                 const float* __restrict__ W2,
                                                 ushort* __restrict__ Wt1,
                                                 ushort* __restrict__ Wt2) {
    int idx = blockIdx.x * 256 + threadIdx.x;
    const float* W = (idx < 16384) ? W1 : W2;
    ushort* O = (idx < 16384) ? Wt1 : Wt2;
    int i = idx & 16383;
    int k = i >> 7, n = i & 127;
    O[n * 128 + k] = f2bf(W[i]);
}

// ---------------- MFMA GEMM + attention coefficients (flat layouts) ----------------
// Block 64x128, 4 waves (2M x 2N). feat [N][128] bf16; el/er [N][8] f32.
#define LDK 136
template <bool BF16IN>
__global__ __launch_bounds__(256) void gemm_attn_mfma(const void* __restrict__ in_,
                                                      const ushort* __restrict__ Wt,
                                                      const float* __restrict__ al,
                                                      const float* __restrict__ ar,
                                                      ushort* __restrict__ feat,
                                                      float* __restrict__ el,
                                                      float* __restrict__ er, int N) {
    __shared__ ushort sA[64 * LDK];
    int tid = threadIdx.x;
    int rowbase = blockIdx.x * 64;

    if (BF16IN) {
        const ushort* in = (const ushort*)in_;
#pragma unroll
        for (int i = 0; i < 4; ++i) {
            int idx8 = i * 256 + tid;
            int flat = idx8 * 8;
            int row = flat >> 7, col = flat & 127;
            int grow = rowbase + row;
            uint4 v = make_uint4(0, 0, 0, 0);
            if (grow < N) v = *reinterpret_cast<const uint4*>(in + (size_t)grow * 128 + col);
            *reinterpret_cast<uint4*>(&sA[row * LDK + col]) = v;
        }
    } else {
        const float* in = (const float*)in_;
#pragma unroll
        for (int i = 0; i < 8; ++i) {
            int idx4 = i * 256 + tid;
            int flat = idx4 * 4;
            int row = flat >> 7, col = flat & 127;
            int grow = rowbase + row;
            float4 v = make_float4(0.f, 0.f, 0.f, 0.f);
            if (grow < N) v = *reinterpret_cast<const float4*>(in + (size_t)grow * 128 + col);
            uint2 w;
            w.x = (unsigned int)f2bf(v.x) | ((unsigned int)f2bf(v.y) << 16);
            w.y = (unsigned int)f2bf(v.z) | ((unsigned int)f2bf(v.w) << 16);
            *reinterpret_cast<uint2*>(&sA[row * LDK + col]) = w;
        }
    }
    __syncthreads();

    int wid = tid >> 6;
    int lane = tid & 63;
    int wm = wid >> 1;
    int wn = wid & 1;
    int l15 = lane & 15;
    int lhi = lane >> 4;

    f32x4 acc[2][4] = {};
    const ushort* wb = Wt + (size_t)(wn * 64 + l15) * 128 + lhi * 8;
    const ushort* a0p = &sA[(wm * 32 + l15) * LDK + lhi * 8];
    const ushort* a1p = &sA[(wm * 32 + 16 + l15) * LDK + lhi * 8];

#pragma unroll
    for (int ks = 0; ks < 4; ++ks) {
        bf16x8 a0 = *reinterpret_cast<const bf16x8*>(a0p + ks * 32);
        bf16x8 a1 = *reinterpret_cast<const bf16x8*>(a1p + ks * 32);
#pragma unroll
        for (int ni = 0; ni < 4; ++ni) {
            bf16x8 b = *reinterpret_cast<const bf16x8*>(wb + ni * 16 * 128 + ks * 32);
            acc[0][ni] = __builtin_amdgcn_mfma_f32_16x16x32_bf16(a0, b, acc[0][ni], 0, 0, 0);
            acc[1][ni] = __builtin_amdgcn_mfma_f32_16x16x32_bf16(a1, b, acc[1][ni], 0, 0, 0);
        }
    }

#pragma unroll
    for (int ni = 0; ni < 4; ++ni) {
        int head = wn * 4 + ni;
        float alv = al[head * 16 + l15];
        float arv = ar[head * 16 + l15];
#pragma unroll
        for (int mi = 0; mi < 2; ++mi) {
#pragma unroll
            for (int reg = 0; reg < 4; ++reg) {
                int row = rowbase + wm * 32 + mi * 16 + lhi * 4 + reg;
                float v = acc[mi][ni][reg];
                float pl = v * alv;
                float pr = v * arv;
#pragma unroll
                for (int off = 8; off; off >>= 1) {
                    pl += __shfl_xor(pl, off);
                    pr += __shfl_xor(pr, off);
                }
                if (row < N) {
                    feat[(size_t)row * 128 + head * 16 + l15] = f2bf(v);
                    if (l15 == 0) {
                        el[row * 8 + head] = pl;
                        er[row * 8 + head] = pr;
                    }
                }
            }
        }
    }
}

// ---------------- edge weights: w[j][h] = bf16(exp(leaky(el[src]+er[dst]))) --------
// Edge-parallel, fully coalesced, zero divergence. bf16 storage halves both the
// write here and the read in aggregate (alpha = w/sum(w) self-cancels the scale).
__global__ __launch_bounds__(256) void edge_weights(const ushort* __restrict__ bucket,
                                                    const ushort* __restrict__ dst16,
                                                    const float* __restrict__ el,
                                                    const float* __restrict__ er,
                                                    ushort* __restrict__ w, int E) {
    int tid0 = blockIdx.x * 256 + threadIdx.x;
    int h = tid0 & 7;
    int stride = (gridDim.x * 256) >> 3;
    for (int j = tid0 >> 3; j < E; j += stride) {
        int s = (int)bucket[j];   // 8 threads share j -> broadcast
        int d = (int)dst16[j];
        float x = el[s * 8 + h] + er[d * 8 + h];   // 32B contiguous per edge
        x = (x > 0.f) ? x : LEAKY * x;
        w[(size_t)j * 8 + h] = f2bf(__expf(x));    // coalesced 128B per 8 edges
    }
}

// ---------------- per-dst-node aggregation (flat, all heads per walk) ----------------
// EXACT round-13 loop shape (measured 39.6us: batch-8, VGPR~36, occupancy 54%).
// Round-15 lesson: batch-16 raised VGPR 36->44, dropped occupancy to 39%, and the
// 33-deep waitcnt wall halved VALUBusy -> 68us. Batch-8 is the sweet spot.
// Only delta vs round-13: w is bf16 (proven -7MB FETCH, pure data-size change).
__global__ __launch_bounds__(256) void aggregate(const ushort* __restrict__ feat,
                                                 const ushort* __restrict__ w,   // [E][8] bf16
                                                 const int* __restrict__ rowstart,
                                                 const ushort* __restrict__ bucket,
                                                 const float* __restrict__ bias,
                                                 ushort* __restrict__ out,
                                                 int N, int do_relu) {
    int wid = (blockIdx.x * 256 + threadIdx.x) >> 6;
    int lane = threadIdx.x & 63;
    if (wid >= N) return;
    int h = lane >> 3;
    int beg = rowstart[wid];
    int end = rowstart[wid + 1];

    const unsigned int* fp = reinterpret_cast<const unsigned int*>(feat) + lane;
    const ushort* wh = w + h;

    float lsum = 0.f, ax = 0.f, ay = 0.f;

    for (int base = beg; base < end; base += 64) {
        int cnt = min(end - base, 64);
        int myedge = base + lane;
        int sv = (myedge < end) ? (int)bucket[myedge] : 0;  // coalesced 128B per 64 edges
        int k = 0;
        for (; k + 8 <= cnt; k += 8) {
            int ss[8];
            float ww[8];
            unsigned int uu[8];
#pragma unroll
            for (int q = 0; q < 8; ++q) ss[q] = __shfl(sv, k + q);
#pragma unroll
            for (int q = 0; q < 8; ++q) ww[q] = bflo((unsigned int)wh[(size_t)(base + k + q) * 8]);
#pragma unroll
            for (int q = 0; q < 8; ++q) uu[q] = fp[(size_t)ss[q] * 64];  // 256B row
#pragma unroll
            for (int q = 0; q < 8; ++q) {
                lsum += ww[q];
                ax = fmaf(ww[q], bflo(uu[q]), ax);
                ay = fmaf(ww[q], bfhi(uu[q]), ay);
            }
        }
        for (; k < cnt; ++k) {
            int s = __shfl(sv, k);
            float wv = bflo((unsigned int)wh[(size_t)(base + k) * 8]);
            unsigned int u = fp[(size_t)s * 64];
            lsum += wv;
            ax = fmaf(wv, bflo(u), ax);
            ay = fmaf(wv, bfhi(u), ay);
        }
    }

    float inv = (end > beg) ? 1.0f / lsum : 0.0f;
    int c = lane * 2;
    float2 bv = *reinterpret_cast<const float2*>(bias + c);
    float ox = fmaf(ax, inv, bv.x);
    float oy = fmaf(ay, inv, bv.y);
    if (do_relu) {
        ox = fmaxf(ox, 0.f);
        oy = fmaxf(oy, 0.f);
    }
    reinterpret_cast<unsigned int*>(out)[(size_t)wid * 64 + lane] =
        (unsigned int)f2bf(ox) | ((unsigned int)f2bf(oy) << 16);
}

// ---------------- readout (flat bf16) ----------------
__global__ __launch_bounds__(256) void mean_reduce(const ushort* __restrict__ h,
                                                   float* __restrict__ meanbuf, int N) {
    int c = threadIdx.x & 127;
    int rbase = blockIdx.x * 2 + (threadIdx.x >> 7);
    float s = 0.0f;
    for (int r = rbase; r < N; r += gridDim.x * 2)
        s += __uint_as_float((unsigned int)h[(size_t)r * 128 + c] << 16);
    atomicAdd(&meanbuf[c], s);
}

__global__ __launch_bounds__(64) void classifier(const float* __restrict__ meanbuf,
                                                 const float* __restrict__ Wc,
                                                 const float* __restrict__ bc,
                                                 float* __restrict__ outp, float invN) {
    int j = threadIdx.x;
    if (j < 10) {
        float s = 0.0f;
        for (int k = 0; k < 128; ++k) s += meanbuf[k] * invN * Wc[k * 10 + j];
        outp[j] = s + bc[j];
    }
}

// ---------------- launch ----------------

extern "C" void kernel_launch(void* const* d_in, const int* in_sizes, int n_in,
                              void* d_out, int out_size, void* d_ws, size_t ws_size,
                              hipStream_t stream) {
    const float* x   = (const float*)d_in[0];
    const int*   src = (const int*)d_in[1];
    const int*   dst = (const int*)d_in[2];
    const float* W1  = (const float*)d_in[3];
    const float* al1 = (const float*)d_in[4];
    const float* ar1 = (const float*)d_in[5];
    const float* b1  = (const float*)d_in[6];
    const float* W2  = (const float*)d_in[7];
    const float* al2 = (const float*)d_in[8];
    const float* ar2 = (const float*)d_in[9];
    const float* b2  = (const float*)d_in[10];
    const float* Wc  = (const float*)d_in[11];
    const float* bc  = (const float*)d_in[12];

    int N = in_sizes[0] / 128;
    int E = in_sizes[1];
    int NB = (N + (1 << BINB) - 1) >> BINB;

    size_t off = 0;
    auto alloc = [&](size_t bytes) -> void* {
        void* p = (char*)d_ws + off;
        off += (bytes + 255) & ~size_t(255);
        return p;
    };
    int*   bin_cnt    = (int*)alloc(sizeof(int) * NB);
    int*   binStart   = (int*)alloc(sizeof(int) * (NB + 1));
    int*   bin_cursor = (int*)alloc(sizeof(int) * NB);
    int*   rowstart   = (int*)alloc(sizeof(int) * (N + 1));
    unsigned int* coarse = (unsigned int*)alloc(sizeof(unsigned int) * E);
    ushort* bucket  = (ushort*)alloc(sizeof(ushort) * E);
    ushort* dst16   = (ushort*)alloc(sizeof(ushort) * E);
    ushort* wbuf    = (ushort*)alloc(sizeof(ushort) * (size_t)E * 8);
    ushort* feat    = (ushort*)alloc(sizeof(ushort) * (size_t)N * 128);
    float* el       = (float*)alloc(sizeof(float) * N * 8);
    float* er       = (float*)alloc(sizeof(float) * N * 8);
    ushort* h1      = (ushort*)alloc(sizeof(ushort) * (size_t)N * 128);
    ushort* h2      = (ushort*)alloc(sizeof(ushort) * (size_t)N * 128);
    float* meanbuf  = (float*)alloc(sizeof(float) * 128);
    ushort* Wt1     = (ushort*)alloc(sizeof(ushort) * 128 * 128);
    ushort* Wt2     = (ushort*)alloc(sizeof(ushort) * 128 * 128);

    hipMemsetAsync(bin_cnt, 0, sizeof(int) * NB, stream);
    hipMemsetAsync(meanbuf, 0, sizeof(float) * 128, stream);

    int GB = ceil_div(E, TILE);

    bin_count<<<GB, 256, 0, stream>>>(dst, bin_cnt, E, NB);
    bin_scan<<<1, 256, 0, stream>>>(bin_cnt, binStart, bin_cursor, rowstart, NB, N, E);
    bin_scatter<<<GB, 256, 0, stream>>>(src, dst, bin_cursor, coarse, E);
    fine_csr<<<NB, 256, 0, stream>>>(coarse, binStart, rowstart, bucket, dst16, N);
    convert_w<<<128, 256, 0, stream>>>(W1, W2, Wt1, Wt2);

    // layer 1 (f32 input)
    gemm_attn_mfma<false><<<ceil_div(N, 64), 256, 0, stream>>>(x, Wt1, al1, ar1, feat, el, er, N);
    edge_weights<<<2048, 256, 0, stream>>>(bucket, dst16, el, er, wbuf, E);
    aggregate<<<ceil_div(N * 64, 256), 256, 0, stream>>>(feat, wbuf, rowstart, bucket, b1, h1, N, 1);
    // layer 2 (flat bf16 input)
    gemm_attn_mfma<true><<<ceil_div(N, 64), 256, 0, stream>>>(h1, Wt2, al2, ar2, feat, el, er, N);
    edge_weights<<<2048, 256, 0, stream>>>(bucket, dst16, el, er, wbuf, E);
    aggregate<<<ceil_div(N * 64, 256), 256, 0, stream>>>(feat, wbuf, rowstart, bucket, b2, h2, N, 0);
    // readout
    mean_reduce<<<256, 256, 0, stream>>>(h2, meanbuf, N);
    classifier<<<1, 64, 0, stream>>>(meanbuf, Wc, bc, (float*)d_out, 1.0f / (float)N);
}